// Round 2
// baseline (1883.549 us; speedup 1.0000x reference)
//
#include <hip/hip_runtime.h>
#include <hip/hip_bf16.h>

typedef __bf16 bf16_t;
typedef __bf16 bf16x4 __attribute__((ext_vector_type(4)));
typedef __bf16 bf16x8 __attribute__((ext_vector_type(8)));
typedef float  f32x4  __attribute__((ext_vector_type(4)));

#define NUM_HEADS 32
#define HEAD_DIM 32
#define SEQ 49
#define DIM 1024
#define NWIN 64
#define BATCH 1024
#define MTOT (BATCH * SEQ)          /* 50176 = 392*128 */
#define SCALE 0.17677669529663687f  /* 32^-0.5 */

// ---------------------------------------------------------------------------
// Stage a 128x32 tile into LDS as bf16. fp32 source: float4 load + cvt;
// bf16 source: uint4 (8 elem) load.
// ---------------------------------------------------------------------------
template<typename T>
__device__ __forceinline__ void stage_tile(const T* __restrict__ src, int ld,
                                           int r0, int k0,
                                           bf16_t (*dst)[40], int tid)
{
    if constexpr (sizeof(T) == 4) {           // float32 source
        #pragma unroll
        for (int s = 0; s < 4; ++s) {
            int c   = tid + s * 256;          // 0..1023
            int row = c >> 3;                 // 0..127
            int col = (c & 7) << 2;           // 0,4,...,28
            const float4 v = *(const float4*)(src + (size_t)(r0 + row) * ld + k0 + col);
            bf16x4 o = { (bf16_t)v.x, (bf16_t)v.y, (bf16_t)v.z, (bf16_t)v.w };
            *(bf16x4*)(&dst[row][col]) = o;
        }
    } else {                                  // bf16 source
        #pragma unroll
        for (int s = 0; s < 2; ++s) {
            int c   = tid + s * 256;          // 0..511
            int row = c >> 2;                 // 0..127
            int col = (c & 3) << 3;           // 0,8,16,24
            *(uint4*)(&dst[row][col]) =
                *(const uint4*)(src + (size_t)(r0 + row) * ld + k0 + col);
        }
    }
}

// ---------------------------------------------------------------------------
// bt-GEMM: C[m][n] = sum_k A[m][k] * W[n][k] + bias[n]
// A: (M,K) row-major with row stride lda; W: (N,K) row-major (stride K).
// 128x128 block tile, BK=32, 4 waves (2x2), each wave 64x64 via 4x4 MFMA
// 16x16x32 bf16 tiles; fp32 accumulate; bias fused; C row stride N.
// Fragment layouts (HW-verified per guide):
//   A-op: m=lane&15, k=(lane>>4)*8+j ; B-op: n=lane&15, k=(lane>>4)*8+j
//   C/D : col=lane&15, row=(lane>>4)*4+reg
// ---------------------------------------------------------------------------
template<typename TA, typename TW, typename TC>
__global__ __launch_bounds__(256)
void gemm_bt(const TA* __restrict__ A, int lda,
             const TW* __restrict__ W,
             const float* __restrict__ bias,
             TC* __restrict__ C, int N, int K)
{
    __shared__ __align__(16) bf16_t As[128][40];  // +8 pad: 80B row stride, 16B-divisible
    __shared__ __align__(16) bf16_t Ws[128][40];

    const int tid  = threadIdx.x;
    const int lane = tid & 63;
    const int wave = tid >> 6;
    const int wm = wave >> 1, wn = wave & 1;
    const int l15 = lane & 15, lq = lane >> 4;

    const int m0 = blockIdx.y * 128;
    const int n0 = blockIdx.x * 128;

    f32x4 acc[4][4] = {};

    for (int k0 = 0; k0 < K; k0 += 32) {
        stage_tile<TA>(A, lda, m0, k0, As, tid);
        stage_tile<TW>(W, K,   n0, k0, Ws, tid);
        __syncthreads();

        bf16x8 af[4], wf[4];
        #pragma unroll
        for (int i = 0; i < 4; ++i)
            af[i] = *(const bf16x8*)(&As[wm * 64 + i * 16 + l15][lq * 8]);
        #pragma unroll
        for (int j = 0; j < 4; ++j)
            wf[j] = *(const bf16x8*)(&Ws[wn * 64 + j * 16 + l15][lq * 8]);

        #pragma unroll
        for (int i = 0; i < 4; ++i)
            #pragma unroll
            for (int j = 0; j < 4; ++j)
                acc[i][j] = __builtin_amdgcn_mfma_f32_16x16x32_bf16(
                    af[i], wf[j], acc[i][j], 0, 0, 0);
        __syncthreads();
    }

    #pragma unroll
    for (int i = 0; i < 4; ++i) {
        #pragma unroll
        for (int j = 0; j < 4; ++j) {
            int col = n0 + wn * 64 + j * 16 + l15;
            float bv = bias[col];
            #pragma unroll
            for (int r = 0; r < 4; ++r) {
                int row = m0 + wm * 64 + i * 16 + lq * 4 + r;
                C[(size_t)row * N + col] = (TC)(acc[i][j][r] + bv);
            }
        }
    }
}

// ---------------------------------------------------------------------------
// out_w (c,o) fp32 -> out_wT (o,c) bf16, 1024x1024
// ---------------------------------------------------------------------------
__global__ __launch_bounds__(256)
void transpose1024(const float* __restrict__ in, bf16_t* __restrict__ out)
{
    __shared__ float tile[32][33];
    const int bx = blockIdx.x, by = blockIdx.y;
    const int tx = threadIdx.x & 31, ty = threadIdx.x >> 5;  // 32 x 8
    for (int r = ty; r < 32; r += 8)
        tile[r][tx] = in[(size_t)(by * 32 + r) * 1024 + bx * 32 + tx];
    __syncthreads();
    for (int r = ty; r < 32; r += 8)
        out[(size_t)(bx * 32 + r) * 1024 + by * 32 + tx] = (bf16_t)tile[tx][r];
}

// ---------------------------------------------------------------------------
// Attention: one block (256 thr) per (b,h). SIMT fp32 correctness-first.
// qkv layout: [b][n][which*DIM + h*32 + d], bf16.
// Output written IN PLACE into the q-slice: qkv[b][n][h*32 + d].
// Safe: block (b,h) is the unique reader of exactly those q columns, and it
// copies them to LDS (then __syncthreads) before the final write.
// ---------------------------------------------------------------------------
__global__ __launch_bounds__(256)
void attn_kernel(bf16_t* __restrict__ qkv, const float* __restrict__ mask,
                 const float* __restrict__ rp_table, const int* __restrict__ rp_index)
{
    __shared__ float qs[SEQ][HEAD_DIM];
    __shared__ float ks[SEQ][HEAD_DIM];
    __shared__ float vs[SEQ][HEAD_DIM];
    __shared__ float S[SEQ][SEQ + 3];

    const int tid = threadIdx.x;
    const int b = blockIdx.x >> 5;
    const int h = blockIdx.x & 31;
    const int w = b & (NWIN - 1);   // window index = b % nw

    const size_t base = (size_t)b * SEQ * 3 * DIM + (size_t)h * HEAD_DIM;
    for (int idx = tid; idx < SEQ * HEAD_DIM; idx += 256) {
        int n = idx >> 5, d = idx & 31;
        size_t p = base + (size_t)n * (3 * DIM);
        qs[n][d] = (float)qkv[p + d] * SCALE;
        ks[n][d] = (float)qkv[p + DIM + d];
        vs[n][d] = (float)qkv[p + 2 * DIM + d];
    }
    __syncthreads();

    // scores + relative-position bias + window mask
    for (int s = tid; s < SEQ * SEQ; s += 256) {
        int i = s / SEQ, j = s - i * SEQ;
        float acc = 0.f;
        #pragma unroll
        for (int d = 0; d < HEAD_DIM; ++d) acc += qs[i][d] * ks[j][d];
        acc += rp_table[rp_index[s] * NUM_HEADS + h];
        acc += mask[((size_t)w * SEQ + i) * SEQ + j];
        S[i][j] = acc;
    }
    __syncthreads();

    // row softmax (one thread per row; 49 rows, all in wave 0)
    if (tid < SEQ) {
        float m = -1e30f;
        for (int j = 0; j < SEQ; ++j) m = fmaxf(m, S[tid][j]);
        float sum = 0.f;
        for (int j = 0; j < SEQ; ++j) { float e = __expf(S[tid][j] - m); S[tid][j] = e; sum += e; }
        float inv = 1.f / sum;
        for (int j = 0; j < SEQ; ++j) S[tid][j] *= inv;
    }
    __syncthreads();

    // O = P @ V, written into the q-slice (in place)
    for (int idx = tid; idx < SEQ * HEAD_DIM; idx += 256) {
        int i = idx >> 5, d = idx & 31;
        float acc = 0.f;
        for (int j = 0; j < SEQ; ++j) acc += S[i][j] * vs[j][d];
        qkv[base + (size_t)i * (3 * DIM) + d] = (bf16_t)acc;
    }
}

// ---------------------------------------------------------------------------
extern "C" void kernel_launch(void* const* d_in, const int* in_sizes, int n_in,
                              void* d_out, int out_size, void* d_ws, size_t ws_size,
                              hipStream_t stream)
{
    const float* x        = (const float*)d_in[0];  // (1024,49,1024) fp32
    const float* mask     = (const float*)d_in[1];  // (64,49,49) fp32
    /* d_in[2] = nw (int scalar, ==64, compile-time constant here) */
    const float* qkv_w    = (const float*)d_in[3];  // (3072,1024) fp32, (N,K) layout
    const float* qkv_b    = (const float*)d_in[4];  // (3072,) fp32
    const float* rp_table = (const float*)d_in[5];  // (169,32) fp32
    const float* out_w    = (const float*)d_in[6];  // (1024,1024) fp32, (K,N) layout
    const float* out_b    = (const float*)d_in[7];  // (1024,) fp32
    const int*   rp_index = (const int*)d_in[8];    // (49,49) int32
    float* out = (float*)d_out;                     // (1024,49,1024) fp32

    // workspace: qkv bf16 (50176x3072) = 308,281,344 B | wT bf16 = 2,097,152 B
    bf16_t* qkv = (bf16_t*)d_ws;
    bf16_t* wT  = (bf16_t*)((char*)d_ws + (size_t)MTOT * 3072 * sizeof(bf16_t));

    transpose1024<<<dim3(32, 32), 256, 0, stream>>>(out_w, wT);

    // QKV projection: (50176,1024)fp32 @ (3072,1024)^T fp32 -> (50176,3072) bf16
    gemm_bt<float, float, bf16_t><<<dim3(3072 / 128, MTOT / 128), 256, 0, stream>>>(
        x, 1024, qkv_w, qkv_b, qkv, 3072, 1024);

    // attention per (b,h); output in place into q-slice of qkv
    attn_kernel<<<dim3(BATCH * NUM_HEADS), 256, 0, stream>>>(
        qkv, mask, rp_table, rp_index);

    // output projection: attn (50176,1024 @ lda=3072) bf16 @ wT(1024,1024)^T -> fp32 out
    gemm_bt<bf16_t, bf16_t, float><<<dim3(1024 / 128, MTOT / 128), 256, 0, stream>>>(
        qkv, 3072, wT, out_b, out, 1024, 1024);
}

// Round 3
// 1470.330 us; speedup vs baseline: 1.2810x; 1.2810x over previous
//
#include <hip/hip_runtime.h>
#include <hip/hip_bf16.h>

typedef __bf16 bf16_t;
typedef __bf16 bf16x4 __attribute__((ext_vector_type(4)));
typedef __bf16 bf16x8 __attribute__((ext_vector_type(8)));
typedef float  f32x4  __attribute__((ext_vector_type(4)));

#define NUM_HEADS 32
#define HEAD_DIM 32
#define SEQ 49
#define SEQ2 (SEQ * SEQ)            /* 2401 */
#define DIM 1024
#define NWIN 64
#define BATCH 1024
#define MTOT (BATCH * SEQ)          /* 50176 = 392*128 */
#define SCALE 0.17677669529663687f  /* 32^-0.5 */

#define GLOBAL_AS __attribute__((address_space(1)))
#define LDS_AS    __attribute__((address_space(3)))

// async global->LDS, 16B per lane, LDS dest = wave-uniform base + lane*16
__device__ __forceinline__ void async_copy16(const bf16_t* g, bf16_t* l)
{
    __builtin_amdgcn_global_load_lds((const GLOBAL_AS uint32_t*)g,
                                     (LDS_AS uint32_t*)l, 16, 0, 0);
}

// ---------------------------------------------------------------------------
// fp32 -> bf16 convert (n % 4 == 0)
// ---------------------------------------------------------------------------
__global__ __launch_bounds__(256)
void f32_to_bf16(const float* __restrict__ in, bf16_t* __restrict__ out, int n)
{
    int i = (blockIdx.x * 256 + threadIdx.x) * 4;
    if (i < n) {
        float4 v = *(const float4*)(in + i);
        bf16x4 o = { (bf16_t)v.x, (bf16_t)v.y, (bf16_t)v.z, (bf16_t)v.w };
        *(bf16x4*)(out + i) = o;
    }
}

// ---------------------------------------------------------------------------
// out_w (c,o) fp32 -> wT (o,c) bf16
// ---------------------------------------------------------------------------
__global__ __launch_bounds__(256)
void transpose1024(const float* __restrict__ in, bf16_t* __restrict__ out)
{
    __shared__ float tile[32][33];
    const int bx = blockIdx.x, by = blockIdx.y;
    const int tx = threadIdx.x & 31, ty = threadIdx.x >> 5;
    for (int r = ty; r < 32; r += 8)
        tile[r][tx] = in[(size_t)(by * 32 + r) * 1024 + bx * 32 + tx];
    __syncthreads();
    for (int r = ty; r < 32; r += 8)
        out[(size_t)(bx * 32 + r) * 1024 + by * 32 + tx] = (bf16_t)tile[tx][r];
}

// ---------------------------------------------------------------------------
// biasg[h][i*49+j] = rp_table[rp_index[i*49+j]*32 + h]
// ---------------------------------------------------------------------------
__global__ __launch_bounds__(256)
void bias_gather(const float* __restrict__ rp_table, const int* __restrict__ rp_index,
                 float* __restrict__ biasg)
{
    int idx = blockIdx.x * 256 + threadIdx.x;
    if (idx < NUM_HEADS * SEQ2) {
        int h = idx / SEQ2;
        int ij = idx - h * SEQ2;
        biasg[idx] = rp_table[rp_index[ij] * NUM_HEADS + h];
    }
}

// ---------------------------------------------------------------------------
// bt-GEMM, m97 structure: C[m][n] = sum_k A[m][k]*W[n][k] + bias[n]
// A,W bf16; A row stride lda; W row stride K. 128x128 tile, BK=32, 4 waves,
// global_load_lds width-16 staging, 16x16x32 bf16 MFMA, fp32 accum.
// ---------------------------------------------------------------------------
template<typename TC>
__global__ __launch_bounds__(256)
void gemm_bt(const bf16_t* __restrict__ A, int lda,
             const bf16_t* __restrict__ W,
             const float* __restrict__ bias,
             TC* __restrict__ C, int N, int K)
{
    __shared__ __align__(16) bf16_t As[128][32];   // no pad: global_load_lds layout
    __shared__ __align__(16) bf16_t Ws[128][32];

    const int tid  = threadIdx.x;
    const int lane = tid & 63;
    const int wave = tid >> 6;
    const int wm = wave >> 1, wn = wave & 1;
    const int l15 = lane & 15, lq = lane >> 4;
    const int m0 = blockIdx.y * 128;
    const int n0 = blockIdx.x * 128;

    f32x4 acc[4][4] = {};

    for (int k0 = 0; k0 < K; k0 += 32) {
        #pragma unroll
        for (int it = 0; it < 2; ++it) {
            int c   = it * 256 + wave * 64 + lane;   // chunk id 0..511
            int row = c >> 2;
            int col = (c & 3) << 3;
            bf16_t* lbA = &As[0][0] + (size_t)(it * 256 + wave * 64) * 8;
            bf16_t* lbW = &Ws[0][0] + (size_t)(it * 256 + wave * 64) * 8;
            async_copy16(A + (size_t)(m0 + row) * lda + k0 + col, lbA);
            async_copy16(W + (size_t)(n0 + row) * K   + k0 + col, lbW);
        }
        __syncthreads();

        bf16x8 af[4], wf[4];
        #pragma unroll
        for (int i = 0; i < 4; ++i)
            af[i] = *(const bf16x8*)(&As[wm * 64 + i * 16 + l15][lq * 8]);
        #pragma unroll
        for (int j = 0; j < 4; ++j)
            wf[j] = *(const bf16x8*)(&Ws[wn * 64 + j * 16 + l15][lq * 8]);

        #pragma unroll
        for (int i = 0; i < 4; ++i)
            #pragma unroll
            for (int j = 0; j < 4; ++j)
                acc[i][j] = __builtin_amdgcn_mfma_f32_16x16x32_bf16(
                    af[i], wf[j], acc[i][j], 0, 0, 0);
        __syncthreads();
    }

    #pragma unroll
    for (int i = 0; i < 4; ++i) {
        #pragma unroll
        for (int j = 0; j < 4; ++j) {
            int col = n0 + wn * 64 + j * 16 + l15;
            float bv = bias[col];
            #pragma unroll
            for (int r = 0; r < 4; ++r) {
                int row = m0 + wm * 64 + i * 16 + lq * 4 + r;
                C[(size_t)row * N + col] = (TC)(acc[i][j][r] + bv);
            }
        }
    }
}

// ---------------------------------------------------------------------------
// MFMA attention: one block (256 thr = 4 waves) per (b,h).
// Pad 49->64. Wave w owns query-row tile [16w,16w+16).
// QK^T: 4 MFMAs/wave (K=32=HEAD_DIM). S entries outside 49x49 set to -1e30
// -> exp gives 0 -> P column-pad is exact. PV: 4 MFMAs/wave (K=64, V^T in LDS).
// Output written in place into the q-slice of qkv (block is its sole reader).
// ---------------------------------------------------------------------------
__global__ __launch_bounds__(256)
void attn_mfma(bf16_t* __restrict__ qkv, const float* __restrict__ maskg,
               const float* __restrict__ biasg)
{
    __shared__ __align__(16) bf16_t qs[64][40];   // stride 40: conflict-free frag reads
    __shared__ __align__(16) bf16_t ks[64][40];
    __shared__ __align__(16) bf16_t vt[32][72];   // V^T: [d][j]
    __shared__ __align__(16) float  Ss[64][65];   // odd stride: conflict-free
    __shared__ __align__(16) bf16_t Ps[64][72];
    __shared__ float rowmax[64], rowinv[64];

    const int tid  = threadIdx.x;
    const int lane = tid & 63;
    const int wave = tid >> 6;
    const int l15 = lane & 15, lq = lane >> 4;
    const int b = blockIdx.x >> 5;
    const int h = blockIdx.x & 31;
    const int w = b & (NWIN - 1);
    const size_t base = (size_t)b * (SEQ * 3 * DIM) + h * HEAD_DIM;

    // zero pads that staging won't write (disjoint -> no barrier needed):
    // qs/ks rows 49..63; vt cols 49..71
    for (int i = tid; i < 60; i += 256) {
        int r = 49 + (i >> 2), c = (i & 3) << 3;
        uint4 z = {0, 0, 0, 0};
        *(uint4*)(&qs[r][c]) = z;
        *(uint4*)(&ks[r][c]) = z;
    }
    for (int i = tid; i < 32 * 23; i += 256) {
        int d = i / 23, c = 49 + (i - d * 23);
        vt[d][c] = (bf16_t)0.f;
    }

    // stage q,k,v (49 rows x 32 bf16 each, as 8-elem chunks)
    for (int idx = tid; idx < 3 * SEQ * 4; idx += 256) {
        int which = idx / (SEQ * 4);
        int rem = idx - which * (SEQ * 4);
        int n = rem >> 2, c8 = (rem & 3) << 3;
        uint4 v = *(const uint4*)(qkv + base + (size_t)n * (3 * DIM) + which * DIM + c8);
        if (which == 0)      *(uint4*)(&qs[n][c8]) = v;
        else if (which == 1) *(uint4*)(&ks[n][c8]) = v;
        else {
            const bf16_t* pv = (const bf16_t*)&v;
            #pragma unroll
            for (int j = 0; j < 8; ++j) vt[c8 + j][n] = pv[j];
        }
    }
    __syncthreads();

    // ---- QK^T ----
    const f32x4 zero4 = {0.f, 0.f, 0.f, 0.f};
    bf16x8 qf = *(const bf16x8*)(&qs[wave * 16 + l15][lq * 8]);
    f32x4 sacc[4];
    #pragma unroll
    for (int jt = 0; jt < 4; ++jt) {
        bf16x8 kf = *(const bf16x8*)(&ks[jt * 16 + l15][lq * 8]);
        sacc[jt] = __builtin_amdgcn_mfma_f32_16x16x32_bf16(qf, kf, zero4, 0, 0, 0);
    }
    // scale + bias + mask, pad with -1e30
    #pragma unroll
    for (int jt = 0; jt < 4; ++jt) {
        int j = jt * 16 + l15;
        #pragma unroll
        for (int r = 0; r < 4; ++r) {
            int i = wave * 16 + lq * 4 + r;
            float val = -1e30f;
            if (i < SEQ && j < SEQ) {
                int ij = i * SEQ + j;
                val = sacc[jt][r] * SCALE + biasg[h * SEQ2 + ij] + maskg[w * SEQ2 + ij];
            }
            Ss[i][j] = val;
        }
    }
    __syncthreads();

    // ---- softmax: per-row max & inv-sum (64 rows, one lane each) ----
    if (tid < 64) {
        float m = -1e30f;
        #pragma unroll 4
        for (int j = 0; j < 64; ++j) m = fmaxf(m, Ss[tid][j]);
        float s = 0.f;
        #pragma unroll 4
        for (int j = 0; j < 64; ++j) s += __expf(Ss[tid][j] - m);
        rowmax[tid] = m;
        rowinv[tid] = 1.f / s;
    }
    __syncthreads();

    // ---- P = exp(S - max) * inv  (bf16), all 64x64 ----
    for (int idx = tid; idx < 64 * 64; idx += 256) {
        int i = idx >> 6, j = idx & 63;
        Ps[i][j] = (bf16_t)(__expf(Ss[i][j] - rowmax[i]) * rowinv[i]);
    }
    __syncthreads();

    // ---- O = P @ V ----
    bf16x8 pf0 = *(const bf16x8*)(&Ps[wave * 16 + l15][lq * 8]);
    bf16x8 pf1 = *(const bf16x8*)(&Ps[wave * 16 + l15][32 + lq * 8]);
    #pragma unroll
    for (int dt = 0; dt < 2; ++dt) {
        bf16x8 vf0 = *(const bf16x8*)(&vt[dt * 16 + l15][lq * 8]);
        bf16x8 vf1 = *(const bf16x8*)(&vt[dt * 16 + l15][32 + lq * 8]);
        f32x4 o = __builtin_amdgcn_mfma_f32_16x16x32_bf16(pf0, vf0, zero4, 0, 0, 0);
        o = __builtin_amdgcn_mfma_f32_16x16x32_bf16(pf1, vf1, o, 0, 0, 0);
        #pragma unroll
        for (int r = 0; r < 4; ++r) {
            int i = wave * 16 + lq * 4 + r;
            if (i < SEQ)
                qkv[base + (size_t)i * (3 * DIM) + dt * 16 + l15] = (bf16_t)o[r];
        }
    }
}

// ---------------------------------------------------------------------------
extern "C" void kernel_launch(void* const* d_in, const int* in_sizes, int n_in,
                              void* d_out, int out_size, void* d_ws, size_t ws_size,
                              hipStream_t stream)
{
    const float* x        = (const float*)d_in[0];  // (1024,49,1024)
    const float* mask     = (const float*)d_in[1];  // (64,49,49)
    const float* qkv_w    = (const float*)d_in[3];  // (3072,1024) = (N,K)
    const float* qkv_b    = (const float*)d_in[4];  // (3072,)
    const float* rp_table = (const float*)d_in[5];  // (169,32)
    const float* out_w    = (const float*)d_in[6];  // (1024,1024) = (K,N)
    const float* out_b    = (const float*)d_in[7];  // (1024,)
    const int*   rp_index = (const int*)d_in[8];    // (49,49)
    float* out = (float*)d_out;                     // (1024,49,1024) fp32

    // ws (proven >= 310.4 MB): [ qkv bf16 50176x3072 | wT bf16 1024x1024 ]
    bf16_t* qkv = (bf16_t*)d_ws;
    bf16_t* wT  = (bf16_t*)((char*)d_ws + (size_t)MTOT * 3072 * sizeof(bf16_t));

    // d_out doubles as scratch until GEMM2 overwrites it (stream-ordered):
    // [ xb bf16 50176x1024 | wb bf16 3072x1024 | biasg fp32 32x2401 ]
    bf16_t* xb    = (bf16_t*)d_out;
    bf16_t* wb    = (bf16_t*)((char*)d_out + (size_t)MTOT * DIM * sizeof(bf16_t));
    float*  biasg = (float*)((char*)d_out + (size_t)MTOT * DIM * sizeof(bf16_t)
                                          + (size_t)3 * DIM * DIM * sizeof(bf16_t));

    // prepasses
    f32_to_bf16<<<(MTOT * DIM / 4 + 255) / 256, 256, 0, stream>>>(x, xb, MTOT * DIM);
    f32_to_bf16<<<(3 * DIM * DIM / 4 + 255) / 256, 256, 0, stream>>>(qkv_w, wb, 3 * DIM * DIM);
    transpose1024<<<dim3(32, 32), 256, 0, stream>>>(out_w, wT);
    bias_gather<<<(NUM_HEADS * SEQ2 + 255) / 256, 256, 0, stream>>>(rp_table, rp_index, biasg);

    // QKV projection: (50176,1024) @ (3072,1024)^T -> (50176,3072) bf16
    gemm_bt<bf16_t><<<dim3(3072 / 128, MTOT / 128), 256, 0, stream>>>(
        xb, DIM, wb, qkv_b, qkv, 3072, DIM);

    // attention per (b,h), in-place into q-slice
    attn_mfma<<<dim3(BATCH * NUM_HEADS), 256, 0, stream>>>(qkv, mask, biasg);

    // output projection: (50176,1024 @ lda 3072) @ wT^T -> fp32 d_out
    gemm_bt<float><<<dim3(1024 / 128, MTOT / 128), 256, 0, stream>>>(
        qkv, 3072, wT, out_b, out, DIM, DIM);
}